// Round 11
// baseline (239.509 us; speedup 1.0000x reference)
//
#include <hip/hip_runtime.h>
#include <hip/hip_bf16.h>

typedef __bf16 bf16x8 __attribute__((ext_vector_type(8)));
typedef float f32x4 __attribute__((ext_vector_type(4)));
typedef __attribute__((address_space(3))) void lds_void_t;
typedef __attribute__((address_space(1))) void gbl_void_t;

#define LRELU(x) ((x) >= 0.f ? (x) : 0.2f * (x))

__device__ __forceinline__ void gload16(void* lds_uniform, const void* gsrc) {
    __builtin_amdgcn_global_load_lds((const gbl_void_t*)gsrc, (lds_void_t*)lds_uniform,
                                     16, 0, 0);
}

__device__ __forceinline__ unsigned short f2u(float f) {
    __hip_bfloat16 h = __float2bfloat16(f);
    return reinterpret_cast<unsigned short&>(h);
}

// ---------------- fused f32 -> bf16 convert (4 tensors, one launch) --------
__global__ void cvt_fused(const float* __restrict__ a, __hip_bfloat16* __restrict__ oa, int na,
                          const float* __restrict__ b, __hip_bfloat16* __restrict__ ob, int nb,
                          const float* __restrict__ c, __hip_bfloat16* __restrict__ oc, int nc,
                          const float* __restrict__ d, __hip_bfloat16* __restrict__ od, int nd) {
    const int stride = gridDim.x * blockDim.x;
    const int total = na + nb + nc + nd;
    for (int i = blockIdx.x * blockDim.x + threadIdx.x; i < total; i += stride) {
        const float* s; __hip_bfloat16* o; int j = i;
        if (j < na) { s = a; o = oa; }
        else {
            j -= na;
            if (j < nb) { s = b; o = ob; }
            else {
                j -= nb;
                if (j < nc) { s = c; o = oc; }
                else { j -= nc; s = d; o = od; }
            }
        }
        float4 v = reinterpret_cast<const float4*>(s)[j];
        ushort4 u;
        u.x = f2u(v.x); u.y = f2u(v.y); u.z = f2u(v.z); u.w = f2u(v.w);
        reinterpret_cast<ushort4*>(o)[j] = u;
    }
}

// ================= m97-structure GEMM: 128x128, 4 waves, 4 blocks/CU =======
// Literal transplant of the guide's measured 874-912 TF structure:
//  - 128x128 tile, BK=32, 4 waves (2x2), per-wave 64x64 = 4x4 frags 16x16x32.
//  - SINGLE-buffered LDS (A 8KB + B 8KB = 16 KB) -> 4 blocks/CU at <=128 VGPR
//    (__launch_bounds__(256,4)). Cross-BLOCK wave overlap does the
//    pipelining (m114): block A's stage/reads hide block B's MFMA drain.
//  - NO manual vmcnt/lgkm/sched fences: plain __syncthreads; compiler emits
//    the drains. (m97's documented recipe.)
//  - 2-way chunk-XOR swizzle (free per m136) kills R2's 8-way conflict:
//    element (row, chunk c) stored at chunk position c^((row>>1)&3); applied
//    as pre-swizzled GLOBAL source (linear gload_lds dest) + same XOR on
//    ds_read (rule 21: both-sides-or-neither).
// Sync ledger (R2-proven): stage t -> syncthreads (drains vmcnt) -> reads+
//  MFMA (ds_reads complete before MFMA issue via compiler lgkm; wave reaches
//  end-barrier only after its reads consumed) -> syncthreads -> stage t+1 ok.
// MODE 1: out = bf16(lrelu(bn(A@B^T)) + xq) ; MODE 2: out = bf16(lrelu(bn))
// ===========================================================================
template <int N, int K, int MODE>
__global__ __launch_bounds__(256, 4)
void gemm97(const __hip_bfloat16* __restrict__ A,
            const __hip_bfloat16* __restrict__ Bw,
            const float* __restrict__ xq,
            __hip_bfloat16* __restrict__ out,
            const float* __restrict__ Gg, const float* __restrict__ Gb,
            const float* __restrict__ Gm, const float* __restrict__ Gv) {
    __shared__ __hip_bfloat16 lA[128 * 32];
    __shared__ __hip_bfloat16 lB[128 * 32];

    // XCD-aware block swizzle (nwg % 8 == 0 by launch config); consecutive
    // orig (same A row-panel) land on the same XCD -> A re-reads hit L2.
    const int nwg = gridDim.x;
    const int cpx = nwg >> 3;
    const int bid = blockIdx.x;
    const int orig = (bid & 7) * cpx + (bid >> 3);
    constexpr int NCB = N / 128;
    const int row0 = (orig / NCB) * 128;
    const int col0 = (orig % NCB) * 128;

    const int tid = threadIdx.x;
    const int lane = tid & 63;
    const int wv = tid >> 6;          // 0..3
    const int wm = wv >> 1, wn = wv & 1;
    const int lr = lane & 15, kg = lane >> 4;

    // ---- staging source (pre-swizzled global chunk) ----
    // lane covers LDS elems wv*1024 + q*512 + lane*8 -> row wv*32+q*16+
    // (lane>>2), chunk pos lane&3; swizzle key (row>>1)&3 = (lane>>3)&3.
    const int schunk = (lane & 3) ^ ((lane >> 3) & 3);
    const __hip_bfloat16* Ag = A + (size_t)(row0 + wv * 32 + (lane >> 2)) * K + schunk * 8;
    const __hip_bfloat16* Bg = Bw + (size_t)(col0 + wv * 32 + (lane >> 2)) * K + schunk * 8;
    __hip_bfloat16* lAp = lA + wv * 1024;
    __hip_bfloat16* lBp = lB + wv * 1024;

    // ---- ds_read fragment offsets (same swizzle on the read side) ----
    // row = (wm|wn)*64 + i*16 + lr -> key (lr>>1)&3.
    const int koff = ((kg ^ ((lr >> 1) & 3)) << 3);
    const int aoff = (wm * 64 + lr) * 32 + koff;
    const int boff = (wn * 64 + lr) * 32 + koff;

    f32x4 acc[4][4];
#pragma unroll
    for (int i = 0; i < 4; ++i)
#pragma unroll
        for (int j = 0; j < 4; ++j) acc[i][j] = (f32x4){0.f, 0.f, 0.f, 0.f};

    for (int k = 0; k < K; k += 32) {
        gload16(lAp,       Ag + k);
        gload16(lAp + 512, Ag + k + (size_t)16 * K);
        gload16(lBp,       Bg + k);
        gload16(lBp + 512, Bg + k + (size_t)16 * K);
        __syncthreads();   // compiler drains vmcnt before barrier

        bf16x8 af[4], bf[4];
#pragma unroll
        for (int i = 0; i < 4; ++i)
            af[i] = *reinterpret_cast<const bf16x8*>(lA + aoff + i * 512);
#pragma unroll
        for (int j = 0; j < 4; ++j)
            bf[j] = *reinterpret_cast<const bf16x8*>(lB + boff + j * 512);
#pragma unroll
        for (int i = 0; i < 4; ++i)
#pragma unroll
            for (int j = 0; j < 4; ++j)
                acc[i][j] = __builtin_amdgcn_mfma_f32_16x16x32_bf16(af[i], bf[j], acc[i][j], 0, 0, 0);
        __syncthreads();   // reads consumed before next stage overwrites
    }

    // ---- epilogue: BN + LeakyReLU (+ xq for MODE 1), row-grouped stores ---
    const int bq = row0 >> 11;  // batch index (tile rows within one batch)
    float scl[4], tcn[4], xqv[4];
#pragma unroll
    for (int j = 0; j < 4; ++j) {
        const int c = col0 + wn * 64 + j * 16 + lr;
        scl[j] = Gg[c] * rsqrtf(Gv[c] + 1e-5f);
        tcn[j] = Gb[c] - Gm[c] * scl[j];
        xqv[j] = (MODE == 1) ? xq[bq * 2048 + c] : 0.f;
    }
#pragma unroll
    for (int i = 0; i < 4; ++i) {
#pragma unroll
        for (int rI = 0; rI < 4; ++rI) {
            const int r = row0 + wm * 64 + i * 16 + kg * 4 + rI;
            const size_t rowoff = (size_t)r * N + col0 + wn * 64 + lr;
#pragma unroll
            for (int j = 0; j < 4; ++j) {
                float val = acc[i][j][rI] * scl[j] + tcn[j];
                val = LRELU(val) + xqv[j];
                out[rowoff + j * 16] = __float2bfloat16(val);
            }
        }
    }
}

// ---------------- GEMM3 (M x 64, K=512) fused with layer-4 + bn4 ----------
__global__ __launch_bounds__(256)
void gemm3_l4(const __hip_bfloat16* __restrict__ A,    // s2b [M,512]
              const __hip_bfloat16* __restrict__ W3b,  // [64,512]
              const float* __restrict__ W4,            // [64]
              const float* __restrict__ g3, const float* __restrict__ b3,
              const float* __restrict__ m3, const float* __restrict__ v3,
              const float* __restrict__ g4, const float* __restrict__ b4,
              const float* __restrict__ m4, const float* __restrict__ v4,
              float* __restrict__ logits) {
    const int lane = threadIdx.x & 63;
    const int wv = threadIdx.x >> 6;
    const int row0 = blockIdx.x * 128 + wv * 32;
    const int lr = lane & 15, kg = lane >> 4;

    f32x4 acc[2][4];
#pragma unroll
    for (int i = 0; i < 2; ++i)
#pragma unroll
        for (int j = 0; j < 4; ++j) acc[i][j] = (f32x4){0.f, 0.f, 0.f, 0.f};

    for (int k = 0; k < 512; k += 32) {
        const int kk = k + kg * 8;
        bf16x8 a[2], b[4];
#pragma unroll
        for (int i = 0; i < 2; ++i)
            a[i] = *reinterpret_cast<const bf16x8*>(A + (size_t)(row0 + i * 16 + lr) * 512 + kk);
#pragma unroll
        for (int j = 0; j < 4; ++j)
            b[j] = *reinterpret_cast<const bf16x8*>(W3b + (size_t)(j * 16 + lr) * 512 + kk);
#pragma unroll
        for (int i = 0; i < 2; ++i)
#pragma unroll
            for (int j = 0; j < 4; ++j)
                acc[i][j] = __builtin_amdgcn_mfma_f32_16x16x32_bf16(a[i], b[j], acc[i][j], 0, 0, 0);
    }

    const float sc4 = g4[0] * rsqrtf(v4[0] + 1e-5f);
    const float tc4 = b4[0] - m4[0] * sc4;
#pragma unroll
    for (int i = 0; i < 2; ++i) {
        float t[4] = {0.f, 0.f, 0.f, 0.f};
#pragma unroll
        for (int j = 0; j < 4; ++j) {
            const int c = j * 16 + lr;
            const float sc = g3[c] * rsqrtf(v3[c] + 1e-5f);
            const float tc = b3[c] - m3[c] * sc;
            const float w4c = W4[c];
#pragma unroll
            for (int rI = 0; rI < 4; ++rI) {
                float v = acc[i][j][rI] * sc + tc;
                t[rI] += LRELU(v) * w4c;
            }
        }
#pragma unroll
        for (int m = 1; m < 16; m <<= 1)
#pragma unroll
            for (int rI = 0; rI < 4; ++rI) t[rI] += __shfl_xor(t[rI], m, 64);
        if (lr == 0) {
#pragma unroll
            for (int rI = 0; rI < 4; ++rI) {
                float lg = t[rI] * sc4 + tc4;
                logits[row0 + i * 16 + kg * 4 + rI] = LRELU(lg);
            }
        }
    }
}

// ---------------- softmax over N=2048 per batch ----------------------------
__global__ void softmax2048(const float* __restrict__ logits, float* __restrict__ scores) {
    __shared__ float sh[2048];
    __shared__ float red[256];
    const int b = blockIdx.x, tid = threadIdx.x;
    float lmax = -1e30f;
#pragma unroll
    for (int it = 0; it < 8; ++it) {
        const int n = tid + it * 256;
        float v = logits[b * 2048 + n];
        sh[n] = v;
        lmax = fmaxf(lmax, v);
    }
    red[tid] = lmax;
    __syncthreads();
    for (int s = 128; s > 0; s >>= 1) {
        if (tid < s) red[tid] = fmaxf(red[tid], red[tid + s]);
        __syncthreads();
    }
    const float gmax = red[0];
    __syncthreads();
    float lsum = 0.f;
#pragma unroll
    for (int it = 0; it < 8; ++it) {
        const int n = tid + it * 256;
        float e = expf(sh[n] - gmax);
        sh[n] = e;
        lsum += e;
    }
    red[tid] = lsum;
    __syncthreads();
    for (int s = 128; s > 0; s >>= 1) {
        if (tid < s) red[tid] += red[tid + s];
        __syncthreads();
    }
    const float inv = 1.f / red[0];
#pragma unroll
    for (int it = 0; it < 8; ++it) {
        const int n = tid + it * 256;
        scores[b * 2048 + n] = sh[n] * inv;
    }
}

// ---------------- pooling over features, then subtract xq ------------------
// out[b,e] = sum_n features[b,n,e]*scores[b,n] - xq[b,e]   (sum scores = 1)
__global__ void pool_partial(const __hip_bfloat16* __restrict__ feats,
                             const float* __restrict__ scores,
                             float* __restrict__ partial) {
    const int b = blockIdx.y, nc = blockIdx.x;  // 32 chunks of 64 rows
    const int e0 = threadIdx.x * 8;
    float acc[8] = {0, 0, 0, 0, 0, 0, 0, 0};
    const size_t base = ((size_t)b * 2048 + nc * 64) * 2048;
    for (int i = 0; i < 64; ++i) {
        const float sc = scores[b * 2048 + nc * 64 + i];
        bf16x8 v = *reinterpret_cast<const bf16x8*>(feats + base + (size_t)i * 2048 + e0);
#pragma unroll
        for (int j = 0; j < 8; ++j) acc[j] += sc * (float)v[j];
    }
    float* p = partial + ((size_t)(b * 32 + nc)) * 2048 + e0;
#pragma unroll
    for (int j = 0; j < 8; ++j) p[j] = acc[j];
}

__global__ void pool_reduce(const float* __restrict__ partial,
                            const float* __restrict__ xq,
                            float* __restrict__ out) {
    const int i = blockIdx.x * blockDim.x + threadIdx.x;  // 0..32767
    const int b = i >> 11, e = i & 2047;
    float s = 0.f;
#pragma unroll
    for (int nc = 0; nc < 32; ++nc) s += partial[((size_t)(b * 32 + nc)) * 2048 + e];
    out[i] = s - xq[i];
}

// ---------------------------------------------------------------------------
extern "C" void kernel_launch(void* const* d_in, const int* in_sizes, int n_in,
                              void* d_out, int out_size, void* d_ws, size_t ws_size,
                              hipStream_t stream) {
    const float* xq = (const float*)d_in[0];
    const float* xk = (const float*)d_in[1];
    const float* W1 = (const float*)d_in[2];
    const float* W2 = (const float*)d_in[3];
    const float* W3 = (const float*)d_in[4];
    const float* W4 = (const float*)d_in[5];
    const float* g1 = (const float*)d_in[6], *b1 = (const float*)d_in[7];
    const float* m1 = (const float*)d_in[8], *v1 = (const float*)d_in[9];
    const float* g2 = (const float*)d_in[10], *b2 = (const float*)d_in[11];
    const float* m2 = (const float*)d_in[12], *v2 = (const float*)d_in[13];
    const float* g3 = (const float*)d_in[14], *b3 = (const float*)d_in[15];
    const float* m3 = (const float*)d_in[16], *v3 = (const float*)d_in[17];
    const float* g4 = (const float*)d_in[18], *b4 = (const float*)d_in[19];
    const float* m4 = (const float*)d_in[20], *v4 = (const float*)d_in[21];

    const int M = 32768;  // B*N = 16*2048

    char* ws = (char*)d_ws;
    size_t off = 0;
    auto alloc = [&](size_t bytes) {
        void* p = ws + off;
        off += (bytes + 255) & ~(size_t)255;
        return p;
    };
    __hip_bfloat16* xkb   = (__hip_bfloat16*)alloc((size_t)M * 512 * 2);
    __hip_bfloat16* w1b   = (__hip_bfloat16*)alloc((size_t)2048 * 512 * 2);
    __hip_bfloat16* w2b   = (__hip_bfloat16*)alloc((size_t)512 * 2048 * 2);
    __hip_bfloat16* w3b   = (__hip_bfloat16*)alloc((size_t)64 * 512 * 2);
    __hip_bfloat16* featb = (__hip_bfloat16*)alloc((size_t)M * 2048 * 2);
    __hip_bfloat16* s2b   = (__hip_bfloat16*)alloc((size_t)M * 512 * 2);
    float* logits         = (float*)alloc((size_t)M * 4);
    float* scores         = (float*)alloc((size_t)16 * 2048 * 4);
    float* partial        = (float*)alloc((size_t)16 * 32 * 2048 * 4);

    // fused converts (one launch)
    cvt_fused<<<4096, 256, 0, stream>>>(
        xk, xkb, M * 512 / 4,
        W1, w1b, 2048 * 512 / 4,
        W2, w2b, 512 * 2048 / 4,
        W3, w3b, 64 * 512 / 4);

    // GEMM1: features = lrelu(bn1(xk @ W1^T)) + xq   [M,2048] bf16
    gemm97<2048, 512, 1><<<4096, 256, 0, stream>>>(
        xkb, w1b, xq, featb, g1, b1, m1, v1);

    // GEMM2: s2 = lrelu(bn2(features @ W2^T))        [M,512] bf16
    gemm97<512, 2048, 2><<<1024, 256, 0, stream>>>(
        featb, w2b, nullptr, s2b, g2, b2, m2, v2);

    // GEMM3 + layer4: logits [M] f32
    gemm3_l4<<<256, 256, 0, stream>>>(s2b, w3b, W4,
                                      g3, b3, m3, v3, g4, b4, m4, v4, logits);

    // softmax over N per batch
    softmax2048<<<16, 256, 0, stream>>>(logits, scores);

    // pooling (+ subtract xq)
    pool_partial<<<dim3(32, 16), 256, 0, stream>>>(featb, scores, partial);
    pool_reduce<<<128, 256, 0, stream>>>(partial, xq, (float*)d_out);
}